// Round 1
// baseline (813.854 us; speedup 1.0000x reference)
//
#include <hip/hip_runtime.h>

// ---------------------------------------------------------------------------
// Swin window-attention block, MI355X.
// B=8 H=W=112 C=384 NH=12 hd=32 WS=7 SS=3 -> N=49, nW=256, Bw=2048,
// token rows = 100352. No padding (112%7==0), so gather/scatter is just the
// cyclic shift + window (un)partition, folded into k2's addresses.
//
// k0: weight transpose->bf16 (N-major so B-fragments are 16B-contiguous),
//     Q-scale folded into W1t rows [0,384); bias table BT[h][bcol][arow] f32
//     with -1e9 for bcol>=49 (pads softmax away).
// k1: Y = x @ Wqkv + b  (bf16 MFMA 16x16x32, fragment-major LDS)
// k2: per (window,head) wave: S=QK^T (+bias+mask), softmax, O=PV,
//     scatter O (f32) to PIXEL layout directly into d_out.
// k3: d_out = d_out @ Wproj + b, in place (BN=384: block owns its rows).
// ---------------------------------------------------------------------------

typedef __bf16 bf16;
typedef __bf16 bf16x8 __attribute__((ext_vector_type(8)));
typedef float  f32x4  __attribute__((ext_vector_type(4)));

#define MFMA16(a, b, c) __builtin_amdgcn_mfma_f32_16x16x32_bf16((a), (b), (c), 0, 0, 0)

static __device__ __forceinline__ bf16x8 cvt8(const float4 lo, const float4 hi) {
    bf16x8 r;
    r[0] = (bf16)lo.x; r[1] = (bf16)lo.y; r[2] = (bf16)lo.z; r[3] = (bf16)lo.w;
    r[4] = (bf16)hi.x; r[5] = (bf16)hi.y; r[6] = (bf16)hi.z; r[7] = (bf16)hi.w;
    return r;
}

// ---------------------------------------------------------------------------
// k0: prep weights + bias table.  Total threads = 442368 + 147456 + 49152.
// ---------------------------------------------------------------------------
__global__ __launch_bounds__(256) void k0_prep(
    const float* __restrict__ qkv_w, const float* __restrict__ proj_w,
    const float* __restrict__ rpt,
    bf16* __restrict__ w1t, bf16* __restrict__ w2t, float* __restrict__ BT)
{
    unsigned tid = blockIdx.x * 256u + threadIdx.x;
    if (tid < 442368u) {                       // w1t[n][k] = qkv_w[k][n] (*scale for Q)
        unsigned n = tid / 384u, k = tid - n * 384u;
        float v = qkv_w[k * 1152u + n];
        if (n < 384u) v *= 0.17677669529663687f;   // 32^-0.5 folded into Q columns
        w1t[tid] = (bf16)v;
    } else if (tid < 589824u) {                // w2t[n][k] = proj_w[k][n]
        unsigned i = tid - 442368u;
        unsigned n = i / 384u, k = i - n * 384u;
        w2t[i] = (bf16)proj_w[k * 384u + n];
    } else if (tid < 638976u) {                // BT[h][b][a]
        unsigned i = tid - 589824u;
        unsigned h = i >> 12, r = i & 4095u, b = r >> 6, a = r & 63u;
        float v;
        if (b >= 49u) v = -1e9f;               // padded key column -> softmax zero
        else if (a >= 49u) v = 0.0f;           // padded query row (unused)
        else {
            int ia = (int)(a / 7u), ja = (int)(a - 7u * (a / 7u));
            int ib = (int)(b / 7u), jb = (int)(b - 7u * (b / 7u));
            int ridx = 84 + 13 * (ia - ib) + (ja - jb);  // in [0,168]
            v = rpt[ridx * 12 + (int)h];
        }
        BT[i] = v;
    }
}

// ---------------------------------------------------------------------------
// k1: Y[100352][1152](bf16) = x(f32) @ W1t^T + qkv_b.  BM=BN=128, BK=64.
// LDS is fragment-major: block (mb,ks) = 64 lanes x 16B contiguous.
// XCD swizzle: the 9 N-tiles of one M-row run consecutively on one XCD.
// ---------------------------------------------------------------------------
__global__ __launch_bounds__(256) void k1_qkv(
    const float* __restrict__ X, const bf16* __restrict__ W,
    const float* __restrict__ bias, bf16* __restrict__ Y)
{
    __shared__ __align__(16) bf16 Asm[8192];   // 16 blocks x 512 bf16
    __shared__ __align__(16) bf16 Bsm[8192];
    unsigned id = blockIdx.x;                  // 7056 = 8 xcd * 98 mi * 9 n
    unsigned xcd = id & 7u, seq = id >> 3;
    unsigned mi = seq / 9u, nblk = seq - mi * 9u;
    unsigned mblk = xcd + (mi << 3);
    unsigned tid = threadIdx.x;
    unsigned lane = tid & 63u, wv = tid >> 6;
    unsigned ln = lane & 15u, lq = lane >> 4;
    unsigned wm = wv >> 1, wn = wv & 1u;       // 2x2 waves, 64x64 each
    unsigned m0 = mblk * 128u, n0 = nblk * 128u;

    f32x4 acc[4][4] = {};

    for (unsigned kt = 0; kt < 6; ++kt) {
        unsigned k0 = kt * 64u;
        __syncthreads();
        // stage 2048 x 16B chunks (A:0..1023 f32->bf16, B:1024..2047 raw)
#pragma unroll
        for (unsigned r = 0; r < 8; ++r) {
            unsigned f = tid + (r << 8);
            if (f < 1024u) {
                unsigned blk = f >> 6, l = f & 63u;
                unsigned row = m0 + (blk >> 1) * 16u + (l & 15u);
                unsigned gk  = k0 + (blk & 1u) * 32u + (l >> 4) * 8u;
                const float* src = X + (size_t)row * 384u + gk;
                float4 lo = *(const float4*)src;
                float4 hi = *(const float4*)(src + 4);
                *(bf16x8*)&Asm[f * 8u] = cvt8(lo, hi);
            } else {
                unsigned g = f - 1024u;
                unsigned blk = g >> 6, l = g & 63u;
                unsigned row = n0 + (blk >> 1) * 16u + (l & 15u);
                unsigned gk  = k0 + (blk & 1u) * 32u + (l >> 4) * 8u;
                *(int4*)&Bsm[g * 8u] = *(const int4*)(W + (size_t)row * 384u + gk);
            }
        }
        __syncthreads();
#pragma unroll
        for (unsigned ks = 0; ks < 2; ++ks) {
            bf16x8 af[4], bfr[4];
#pragma unroll
            for (unsigned t = 0; t < 4; ++t)
                af[t] = *(const bf16x8*)&Asm[(((wm * 4u + t) << 1) + ks) * 512u + lane * 8u];
#pragma unroll
            for (unsigned t = 0; t < 4; ++t)
                bfr[t] = *(const bf16x8*)&Bsm[(((wn * 4u + t) << 1) + ks) * 512u + lane * 8u];
#pragma unroll
            for (unsigned i = 0; i < 4; ++i)
#pragma unroll
                for (unsigned j = 0; j < 4; ++j)
                    acc[i][j] = MFMA16(af[i], bfr[j], acc[i][j]);
        }
    }
    // epilogue: + qkv_b (Q part pre-scaled), store bf16
#pragma unroll
    for (unsigned j = 0; j < 4; ++j) {
        unsigned col = n0 + wn * 64u + j * 16u + ln;
        float bv = bias[col];
        if (col < 384u) bv *= 0.17677669529663687f;
#pragma unroll
        for (unsigned i = 0; i < 4; ++i) {
            unsigned row = m0 + wm * 64u + i * 16u + lq * 4u;
#pragma unroll
            for (unsigned rg = 0; rg < 4; ++rg)
                Y[(size_t)(row + rg) * 1152u + col] = (bf16)(acc[i][j][rg] + bv);
        }
    }
}

// ---------------------------------------------------------------------------
// k2: one wave per (window, head).  grid = (12, 2048), block = 64.
// ---------------------------------------------------------------------------
__global__ __launch_bounds__(64) void k2_attn(
    const bf16* __restrict__ Y, const float* __restrict__ BT,
    float* __restrict__ O)
{
    __shared__ __align__(16) bf16 Pl[64 * 72]; // P, padded stride 72 (2-way only)
    __shared__ __align__(16) bf16 Vt[32 * 72]; // V^T
    unsigned h = blockIdx.x, bwin = blockIdx.y;
    unsigned bb = bwin >> 8, wi = bwin & 255u, wh = wi >> 4, ww = wi & 15u;
    unsigned lane = threadIdx.x, ln = lane & 15u, lq = lane >> 4;
    unsigned hw32 = h * 32u;

    auto pixrow = [&](unsigned t) -> unsigned {   // token -> shifted pixel row
        unsigned ti = t / 7u, tj = t - ti * 7u;
        unsigned gh = wh * 7u + ti + 3u; if (gh >= 112u) gh -= 112u;
        unsigned gw = ww * 7u + tj + 3u; if (gw >= 112u) gw -= 112u;
        return bb * 12544u + gh * 112u + gw;
    };

    // V row -> LDS transposed (padded rows are finite garbage; P there is 0)
    {
        unsigned t = lane < 49u ? lane : 0u;
        const bf16* vs = Y + (size_t)pixrow(t) * 1152u + 768u + hw32;
        bf16x8 v0 = *(const bf16x8*)(vs);
        bf16x8 v1 = *(const bf16x8*)(vs + 8);
        bf16x8 v2 = *(const bf16x8*)(vs + 16);
        bf16x8 v3 = *(const bf16x8*)(vs + 24);
#pragma unroll
        for (int d = 0; d < 8; ++d) {
            Vt[(unsigned)(d     ) * 72u + lane] = v0[d];
            Vt[(unsigned)(d + 8 ) * 72u + lane] = v1[d];
            Vt[(unsigned)(d + 16) * 72u + lane] = v2[d];
            Vt[(unsigned)(d + 24) * 72u + lane] = v3[d];
        }
    }

    // Q/K fragments straight from global (16B contiguous per lane)
    bf16x8 qf[4], kf[4];
#pragma unroll
    for (int i = 0; i < 4; ++i) {
        unsigned t = (unsigned)i * 16u + ln; t = t < 49u ? t : 0u;
        qf[i] = *(const bf16x8*)(Y + (size_t)pixrow(t) * 1152u + hw32 + lq * 8u);
    }
#pragma unroll
    for (int i = 0; i < 4; ++i) {
        unsigned t = (unsigned)i * 16u + ln; t = t < 49u ? t : 0u;
        kf[i] = *(const bf16x8*)(Y + (size_t)pixrow(t) * 1152u + 384u + hw32 + lq * 8u);
    }

    f32x4 s[4][4] = {};
#pragma unroll
    for (int i = 0; i < 4; ++i)
#pragma unroll
        for (int j = 0; j < 4; ++j)
            s[i][j] = MFMA16(qf[i], kf[j], s[i][j]);

    // + relative-position bias (padding cols = -1e9)
    const float* bth = BT + h * 4096u;
#pragma unroll
    for (int i = 0; i < 4; ++i)
#pragma unroll
        for (int j = 0; j < 4; ++j) {
            f32x4 b = *(const f32x4*)(bth + ((unsigned)j * 16u + ln) * 64u +
                                      (unsigned)i * 16u + lq * 4u);
            s[i][j] += b;
        }

    // shifted-window mask: only edge windows (wave-uniform branch)
    if (wh == 15u || ww == 15u) {
        int ra[4][4], rb[4];
#pragma unroll
        for (int i = 0; i < 4; ++i)
#pragma unroll
            for (int rg = 0; rg < 4; ++rg) {
                unsigned a = (unsigned)i * 16u + lq * 4u + (unsigned)rg;
                unsigned ti = a / 7u, tj = a - ti * 7u;
                unsigned gh = wh * 7u + ti, gw = ww * 7u + tj;
                int rh = gh < 105u ? 0 : (gh < 109u ? 1 : 2);
                int rw = gw < 105u ? 0 : (gw < 109u ? 1 : 2);
                ra[i][rg] = rh * 3 + rw;
            }
#pragma unroll
        for (int j = 0; j < 4; ++j) {
            unsigned bc = (unsigned)j * 16u + ln;
            unsigned ti = bc / 7u, tj = bc - ti * 7u;
            unsigned gh = wh * 7u + ti, gw = ww * 7u + tj;
            int rh = gh < 105u ? 0 : (gh < 109u ? 1 : 2);
            int rw = gw < 105u ? 0 : (gw < 109u ? 1 : 2);
            rb[j] = rh * 3 + rw;
        }
#pragma unroll
        for (int i = 0; i < 4; ++i)
#pragma unroll
            for (int j = 0; j < 4; ++j)
#pragma unroll
                for (int rg = 0; rg < 4; ++rg)
                    if (ra[i][rg] != rb[j]) s[i][j][rg] -= 100.0f;
    }

    // softmax (row = i*16 + lq*4 + rg, cols across 16 lanes x 4 j)
    float rinv[4][4];
#pragma unroll
    for (int i = 0; i < 4; ++i)
#pragma unroll
        for (int rg = 0; rg < 4; ++rg) {
            float m = fmaxf(fmaxf(s[i][0][rg], s[i][1][rg]),
                            fmaxf(s[i][2][rg], s[i][3][rg]));
#pragma unroll
            for (int d = 8; d >= 1; d >>= 1) m = fmaxf(m, __shfl_xor(m, d, 64));
            float sum = 0.0f;
#pragma unroll
            for (int j = 0; j < 4; ++j) {
                float e = __expf(s[i][j][rg] - m);
                s[i][j][rg] = e;
                sum += e;
            }
#pragma unroll
            for (int d = 8; d >= 1; d >>= 1) sum += __shfl_xor(sum, d, 64);
            rinv[i][rg] = 1.0f / sum;   // folded into O epilogue
        }

    // P (unnormalized e) -> LDS in A-operand layout source
#pragma unroll
    for (int i = 0; i < 4; ++i)
#pragma unroll
        for (int rg = 0; rg < 4; ++rg) {
            unsigned a = (unsigned)i * 16u + lq * 4u + (unsigned)rg;
#pragma unroll
            for (int j = 0; j < 4; ++j)
                Pl[a * 72u + (unsigned)j * 16u + ln] = (bf16)s[i][j][rg];
        }

    __syncthreads();

    // O = P @ V   (64x32, K=64 in two 32-steps)
    f32x4 o[4][2] = {};
#pragma unroll
    for (int ks = 0; ks < 2; ++ks) {
        bf16x8 pf[4], vf[2];
#pragma unroll
        for (int i = 0; i < 4; ++i)
            pf[i] = *(const bf16x8*)&Pl[((unsigned)i * 16u + ln) * 72u +
                                        (unsigned)ks * 32u + lq * 8u];
#pragma unroll
        for (int c = 0; c < 2; ++c)
            vf[c] = *(const bf16x8*)&Vt[((unsigned)c * 16u + ln) * 72u +
                                        (unsigned)ks * 32u + lq * 8u];
#pragma unroll
        for (int i = 0; i < 4; ++i)
#pragma unroll
            for (int c = 0; c < 2; ++c)
                o[i][c] = MFMA16(pf[i], vf[c], o[i][c]);
    }

    // scatter O (f32) to PIXEL layout in d_out (fuses window-reverse + roll)
#pragma unroll
    for (int i = 0; i < 4; ++i)
#pragma unroll
        for (int rg = 0; rg < 4; ++rg) {
            unsigned a = (unsigned)i * 16u + lq * 4u + (unsigned)rg;
            if (a < 49u) {
                float ri = rinv[i][rg];
                size_t base = (size_t)pixrow(a) * 384u + hw32;
                O[base + ln]        = o[i][0][rg] * ri;
                O[base + 16u + ln]  = o[i][1][rg] * ri;
            }
        }
}

// ---------------------------------------------------------------------------
// k3: in-place proj GEMM on d_out.  BM=128, BN=384 (block owns its rows),
// 12 waves (2x6), LDS A 16KB + B 48KB = 64KB.
// ---------------------------------------------------------------------------
__global__ __launch_bounds__(768) void k3_proj(
    const float* A, const bf16* __restrict__ W,
    const float* __restrict__ bias, float* Out)
{
    __shared__ __align__(16) bf16 Asm[8192];    // 16 blocks
    __shared__ __align__(16) bf16 Bsm[24576];   // 48 blocks
    unsigned mblk = blockIdx.x;                 // 0..783
    unsigned tid = threadIdx.x;
    unsigned lane = tid & 63u, wv = tid >> 6;
    unsigned ln = lane & 15u, lq = lane >> 4;
    unsigned wm = wv & 1u, wn = wv >> 1;        // 2 x 6 waves, 64x64 each
    unsigned m0 = mblk * 128u;

    f32x4 acc[4][4] = {};

    for (unsigned kt = 0; kt < 6; ++kt) {
        unsigned k0 = kt * 64u;
        __syncthreads();
        for (unsigned f = tid; f < 4096u; f += 768u) {
            if (f < 1024u) {
                unsigned blk = f >> 6, l = f & 63u;
                unsigned row = m0 + (blk >> 1) * 16u + (l & 15u);
                unsigned gk  = k0 + (blk & 1u) * 32u + (l >> 4) * 8u;
                const float* src = A + (size_t)row * 384u + gk;
                float4 lo = *(const float4*)src;
                float4 hi = *(const float4*)(src + 4);
                *(bf16x8*)&Asm[f * 8u] = cvt8(lo, hi);
            } else {
                unsigned g = f - 1024u;
                unsigned blk = g >> 6, l = g & 63u;
                unsigned row = (blk >> 1) * 16u + (l & 15u);
                unsigned gk  = k0 + (blk & 1u) * 32u + (l >> 4) * 8u;
                *(int4*)&Bsm[g * 8u] = *(const int4*)(W + (size_t)row * 384u + gk);
            }
        }
        __syncthreads();
#pragma unroll
        for (unsigned ks = 0; ks < 2; ++ks) {
            bf16x8 af[4], bfr[4];
#pragma unroll
            for (unsigned t = 0; t < 4; ++t)
                af[t] = *(const bf16x8*)&Asm[(((wm * 4u + t) << 1) + ks) * 512u + lane * 8u];
#pragma unroll
            for (unsigned t = 0; t < 4; ++t)
                bfr[t] = *(const bf16x8*)&Bsm[(((wn * 4u + t) << 1) + ks) * 512u + lane * 8u];
#pragma unroll
            for (unsigned i = 0; i < 4; ++i)
#pragma unroll
                for (unsigned j = 0; j < 4; ++j)
                    acc[i][j] = MFMA16(af[i], bfr[j], acc[i][j]);
        }
    }
    // epilogue: + proj_b, write same rows (pixel layout already)
#pragma unroll
    for (unsigned j = 0; j < 4; ++j) {
        unsigned col = wn * 64u + j * 16u + ln;
        float bv = bias[col];
#pragma unroll
        for (unsigned i = 0; i < 4; ++i) {
            unsigned row = m0 + wm * 64u + i * 16u + lq * 4u;
#pragma unroll
            for (unsigned rg = 0; rg < 4; ++rg)
                Out[(size_t)(row + rg) * 384u + col] = acc[i][j][rg] + bv;
        }
    }
}

// ---------------------------------------------------------------------------
// launch
// ---------------------------------------------------------------------------
extern "C" void kernel_launch(void* const* d_in, const int* in_sizes, int n_in,
                              void* d_out, int out_size, void* d_ws, size_t ws_size,
                              hipStream_t stream) {
    const float* x      = (const float*)d_in[0];
    const float* qkv_w  = (const float*)d_in[1];
    const float* qkv_b  = (const float*)d_in[2];
    const float* proj_w = (const float*)d_in[3];
    const float* proj_b = (const float*)d_in[4];
    const float* rpt    = (const float*)d_in[5];
    (void)in_sizes; (void)n_in; (void)out_size; (void)ws_size;

    char* ws = (char*)d_ws;
    // Y: 100352*1152*2 = 231,211,008 B; then w1t, w2t, BT.  Total 232.6 MB.
    bf16*  Y   = (bf16*)(ws);
    bf16*  w1t = (bf16*)(ws + 231211008u);
    bf16*  w2t = (bf16*)(ws + 232095744u);
    float* BT  = (float*)(ws + 232390656u);
    float* out = (float*)d_out;

    k0_prep<<<2496, 256, 0, stream>>>(qkv_w, proj_w, rpt, w1t, w2t, BT);
    k1_qkv<<<7056, 256, 0, stream>>>(x, w1t, qkv_b, Y);
    k2_attn<<<dim3(12, 2048), 64, 0, stream>>>(Y, BT, out);
    k3_proj<<<784, 768, 0, stream>>>(out, w2t, proj_b, out);
}

// Round 2
// 790.244 us; speedup vs baseline: 1.0299x; 1.0299x over previous
//
#include <hip/hip_runtime.h>

// ---------------------------------------------------------------------------
// Swin window-attention block, MI355X.  B=8 H=W=112 C=384 NH=12 hd=32 WS=7
// SS=3 -> N=49, nW=256, Bw=2048, rows=100352.
//
// Round-2 restructure: GEMMs are barrier-free.  B (weights) staged in LDS
// ONCE (64 cols x K=384 = 48 KB), A-fragments loaded straight from global
// into registers (16-32 B/lane), no __syncthreads in the K-loop -> compiler
// software-pipelines loads with fine-grained vmcnt (the m97 2-barrier
// structure was latency-bound at MfmaUtil 9.5%).
//
// k2 writes attn-out (bf16) into Y's Q-slot (cols [0,384)): per-head cols
// and per-window rows are disjoint, and each block reads its Q before any
// writes -> race-free, zero extra workspace, halves k2-write/k3-read bytes.
// ---------------------------------------------------------------------------

typedef __bf16 bf16;
typedef __bf16 bf16x8 __attribute__((ext_vector_type(8)));
typedef float  f32x4  __attribute__((ext_vector_type(4)));

#define MFMA16(a, b, c) __builtin_amdgcn_mfma_f32_16x16x32_bf16((a), (b), (c), 0, 0, 0)

static __device__ __forceinline__ bf16x8 cvt8(const float4 lo, const float4 hi) {
    bf16x8 r;
    r[0] = (bf16)lo.x; r[1] = (bf16)lo.y; r[2] = (bf16)lo.z; r[3] = (bf16)lo.w;
    r[4] = (bf16)hi.x; r[5] = (bf16)hi.y; r[6] = (bf16)hi.z; r[7] = (bf16)hi.w;
    return r;
}

// ---------------------------------------------------------------------------
// k0: prep weights + bias table (unchanged from round 1, proven correct).
// ---------------------------------------------------------------------------
__global__ __launch_bounds__(256) void k0_prep(
    const float* __restrict__ qkv_w, const float* __restrict__ proj_w,
    const float* __restrict__ rpt,
    bf16* __restrict__ w1t, bf16* __restrict__ w2t, float* __restrict__ BT)
{
    unsigned tid = blockIdx.x * 256u + threadIdx.x;
    if (tid < 442368u) {                       // w1t[n][k] = qkv_w[k][n] (*scale for Q)
        unsigned n = tid / 384u, k = tid - n * 384u;
        float v = qkv_w[k * 1152u + n];
        if (n < 384u) v *= 0.17677669529663687f;
        w1t[tid] = (bf16)v;
    } else if (tid < 589824u) {                // w2t[n][k] = proj_w[k][n]
        unsigned i = tid - 442368u;
        unsigned n = i / 384u, k = i - n * 384u;
        w2t[i] = (bf16)proj_w[k * 384u + n];
    } else if (tid < 638976u) {                // BT[h][b][a]
        unsigned i = tid - 589824u;
        unsigned h = i >> 12, r = i & 4095u, b = r >> 6, a = r & 63u;
        float v;
        if (b >= 49u) v = -1e9f;
        else if (a >= 49u) v = 0.0f;
        else {
            int ia = (int)(a / 7u), ja = (int)(a - 7u * (a / 7u));
            int ib = (int)(b / 7u), jb = (int)(b - 7u * (b / 7u));
            int ridx = 84 + 13 * (ia - ib) + (ja - jb);
            v = rpt[ridx * 12 + (int)h];
        }
        BT[i] = v;
    }
}

// ---------------------------------------------------------------------------
// k1: Y[100352][1152](bf16) = x(f32) @ W1t^T + b.  BM=256 (4 waves stacked),
// BN=64.  B in LDS once (48 KB); K-loop barrier-free, A-frags from global.
// grid = 392*18 = 7056, XCD-swizzled so one XCD walks one A-strip.
// ---------------------------------------------------------------------------
__global__ __launch_bounds__(256, 3) void k1_qkv(
    const float* __restrict__ X, const bf16* __restrict__ W,
    const float* __restrict__ bias, bf16* __restrict__ Y)
{
    __shared__ __align__(16) bf16 Bs[24576];   // 48 blocks x 64 lanes x 16B
    unsigned id = blockIdx.x;                  // 7056 = 8 xcd * 49 mi * 18 n
    unsigned xcd = id & 7u, seq = id >> 3;     // seq 0..881
    unsigned mi = seq / 18u, nb = seq - mi * 18u;
    unsigned mblk = xcd + (mi << 3);           // 0..391
    unsigned tid = threadIdx.x;
    unsigned lane = tid & 63u, wv = tid >> 6;
    unsigned ln = lane & 15u, lq = lane >> 4;
    unsigned m0 = mblk * 256u, n0 = nb * 64u;

    // stage B (64 rows x 384 k), coalesced global reads
    for (unsigned c = tid; c < 3072u; c += 256u) {
        unsigned row = c / 48u, kc = c - row * 48u, k = kc * 8u;
        unsigned blk = (k >> 5) * 4u + (row >> 4);
        unsigned l = (row & 15u) | ((kc & 3u) << 4);
        *(int4*)&Bs[(blk * 64u + l) * 8u] = *(const int4*)(W + (size_t)(n0 + row) * 384u + k);
    }
    __syncthreads();

    f32x4 acc[4][4] = {};
    unsigned rbase = m0 + wv * 64u;

#pragma unroll
    for (unsigned kt = 0; kt < 12; ++kt) {
        bf16x8 af[4], bfr[4];
#pragma unroll
        for (unsigned i = 0; i < 4; ++i) {
            const float* p = X + (size_t)(rbase + i * 16u + ln) * 384u + kt * 32u + lq * 8u;
            af[i] = cvt8(*(const float4*)p, *(const float4*)(p + 4));
        }
#pragma unroll
        for (unsigned j = 0; j < 4; ++j)
            bfr[j] = *(const bf16x8*)&Bs[((kt * 4u + j) * 64u + lane) * 8u];
#pragma unroll
        for (unsigned i = 0; i < 4; ++i)
#pragma unroll
            for (unsigned j = 0; j < 4; ++j)
                acc[i][j] = MFMA16(af[i], bfr[j], acc[i][j]);
    }

    // epilogue: + qkv_b (Q cols pre-scaled), store bf16
#pragma unroll
    for (unsigned j = 0; j < 4; ++j) {
        unsigned col = n0 + j * 16u + ln;
        float bv = bias[col];
        if (col < 384u) bv *= 0.17677669529663687f;
#pragma unroll
        for (unsigned i = 0; i < 4; ++i) {
            unsigned row = rbase + i * 16u + lq * 4u;
#pragma unroll
            for (unsigned rg = 0; rg < 4; ++rg)
                Y[(size_t)(row + rg) * 1152u + col] = (bf16)(acc[i][j][rg] + bv);
        }
    }
}

// ---------------------------------------------------------------------------
// k2: one wave per (window, head).  grid = (12, 2048), block = 64.
// Writes attn-out bf16 into Y's Q-slot (cols [0,384)).
// ---------------------------------------------------------------------------
__global__ __launch_bounds__(64) void k2_attn(
    bf16* __restrict__ Y, const float* __restrict__ BT)
{
    __shared__ __align__(16) bf16 Pl[64 * 72];
    __shared__ __align__(16) bf16 Vt[32 * 72];
    unsigned h = blockIdx.x, bwin = blockIdx.y;
    unsigned bb = bwin >> 8, wi = bwin & 255u, wh = wi >> 4, ww = wi & 15u;
    unsigned lane = threadIdx.x, ln = lane & 15u, lq = lane >> 4;
    unsigned hw32 = h * 32u;

    auto pixrow = [&](unsigned t) -> unsigned {
        unsigned ti = t / 7u, tj = t - ti * 7u;
        unsigned gh = wh * 7u + ti + 3u; if (gh >= 112u) gh -= 112u;
        unsigned gw = ww * 7u + tj + 3u; if (gw >= 112u) gw -= 112u;
        return bb * 12544u + gh * 112u + gw;
    };

    // V -> LDS transposed
    {
        unsigned t = lane < 49u ? lane : 0u;
        const bf16* vs = Y + (size_t)pixrow(t) * 1152u + 768u + hw32;
        bf16x8 v0 = *(const bf16x8*)(vs);
        bf16x8 v1 = *(const bf16x8*)(vs + 8);
        bf16x8 v2 = *(const bf16x8*)(vs + 16);
        bf16x8 v3 = *(const bf16x8*)(vs + 24);
#pragma unroll
        for (int d = 0; d < 8; ++d) {
            Vt[(unsigned)(d     ) * 72u + lane] = v0[d];
            Vt[(unsigned)(d + 8 ) * 72u + lane] = v1[d];
            Vt[(unsigned)(d + 16) * 72u + lane] = v2[d];
            Vt[(unsigned)(d + 24) * 72u + lane] = v3[d];
        }
    }

    bf16x8 qf[4], kf[4];
#pragma unroll
    for (int i = 0; i < 4; ++i) {
        unsigned t = (unsigned)i * 16u + ln; t = t < 49u ? t : 0u;
        qf[i] = *(const bf16x8*)(Y + (size_t)pixrow(t) * 1152u + hw32 + lq * 8u);
    }
#pragma unroll
    for (int i = 0; i < 4; ++i) {
        unsigned t = (unsigned)i * 16u + ln; t = t < 49u ? t : 0u;
        kf[i] = *(const bf16x8*)(Y + (size_t)pixrow(t) * 1152u + 384u + hw32 + lq * 8u);
    }

    f32x4 s[4][4] = {};
#pragma unroll
    for (int i = 0; i < 4; ++i)
#pragma unroll
        for (int j = 0; j < 4; ++j)
            s[i][j] = MFMA16(qf[i], kf[j], s[i][j]);

    const float* bth = BT + h * 4096u;
#pragma unroll
    for (int i = 0; i < 4; ++i)
#pragma unroll
        for (int j = 0; j < 4; ++j) {
            f32x4 b = *(const f32x4*)(bth + ((unsigned)j * 16u + ln) * 64u +
                                      (unsigned)i * 16u + lq * 4u);
            s[i][j] += b;
        }

    if (wh == 15u || ww == 15u) {
        int ra[4][4], rb[4];
#pragma unroll
        for (int i = 0; i < 4; ++i)
#pragma unroll
            for (int rg = 0; rg < 4; ++rg) {
                unsigned a = (unsigned)i * 16u + lq * 4u + (unsigned)rg;
                unsigned ti = a / 7u, tj = a - ti * 7u;
                unsigned gh = wh * 7u + ti, gw = ww * 7u + tj;
                int rh = gh < 105u ? 0 : (gh < 109u ? 1 : 2);
                int rw = gw < 105u ? 0 : (gw < 109u ? 1 : 2);
                ra[i][rg] = rh * 3 + rw;
            }
#pragma unroll
        for (int j = 0; j < 4; ++j) {
            unsigned bc = (unsigned)j * 16u + ln;
            unsigned ti = bc / 7u, tj = bc - ti * 7u;
            unsigned gh = wh * 7u + ti, gw = ww * 7u + tj;
            int rh = gh < 105u ? 0 : (gh < 109u ? 1 : 2);
            int rw = gw < 105u ? 0 : (gw < 109u ? 1 : 2);
            rb[j] = rh * 3 + rw;
        }
#pragma unroll
        for (int i = 0; i < 4; ++i)
#pragma unroll
            for (int j = 0; j < 4; ++j)
#pragma unroll
                for (int rg = 0; rg < 4; ++rg)
                    if (ra[i][rg] != rb[j]) s[i][j][rg] -= 100.0f;
    }

    float rinv[4][4];
#pragma unroll
    for (int i = 0; i < 4; ++i)
#pragma unroll
        for (int rg = 0; rg < 4; ++rg) {
            float m = fmaxf(fmaxf(s[i][0][rg], s[i][1][rg]),
                            fmaxf(s[i][2][rg], s[i][3][rg]));
#pragma unroll
            for (int d = 8; d >= 1; d >>= 1) m = fmaxf(m, __shfl_xor(m, d, 64));
            float sum = 0.0f;
#pragma unroll
            for (int j = 0; j < 4; ++j) {
                float e = __expf(s[i][j][rg] - m);
                s[i][j][rg] = e;
                sum += e;
            }
#pragma unroll
            for (int d = 8; d >= 1; d >>= 1) sum += __shfl_xor(sum, d, 64);
            rinv[i][rg] = 1.0f / sum;
        }

#pragma unroll
    for (int i = 0; i < 4; ++i)
#pragma unroll
        for (int rg = 0; rg < 4; ++rg) {
            unsigned a = (unsigned)i * 16u + lq * 4u + (unsigned)rg;
#pragma unroll
            for (int j = 0; j < 4; ++j)
                Pl[a * 72u + (unsigned)j * 16u + ln] = (bf16)s[i][j][rg];
        }

    __syncthreads();

    f32x4 o[4][2] = {};
#pragma unroll
    for (int ks = 0; ks < 2; ++ks) {
        bf16x8 pf[4], vf[2];
#pragma unroll
        for (int i = 0; i < 4; ++i)
            pf[i] = *(const bf16x8*)&Pl[((unsigned)i * 16u + ln) * 72u +
                                        (unsigned)ks * 32u + lq * 8u];
#pragma unroll
        for (int c = 0; c < 2; ++c)
            vf[c] = *(const bf16x8*)&Vt[((unsigned)c * 16u + ln) * 72u +
                                        (unsigned)ks * 32u + lq * 8u];
#pragma unroll
        for (int i = 0; i < 4; ++i)
#pragma unroll
            for (int c = 0; c < 2; ++c)
                o[i][c] = MFMA16(pf[i], vf[c], o[i][c]);
    }

    // attn-out (bf16) into Y's Q-slot: rows disjoint per window, cols per head
#pragma unroll
    for (int i = 0; i < 4; ++i)
#pragma unroll
        for (int rg = 0; rg < 4; ++rg) {
            unsigned a = (unsigned)i * 16u + lq * 4u + (unsigned)rg;
            if (a < 49u) {
                float ri = rinv[i][rg];
                size_t base = (size_t)pixrow(a) * 1152u + hw32;
                Y[base + ln]       = (bf16)(o[i][0][rg] * ri);
                Y[base + 16u + ln] = (bf16)(o[i][1][rg] * ri);
            }
        }
}

// ---------------------------------------------------------------------------
// k3: Out[100352][384](f32) = Ab(bf16, Y's Q-slot) @ W2t^T + b.
// Same barrier-free structure as k1.  grid = 392*6 = 2352.
// ---------------------------------------------------------------------------
__global__ __launch_bounds__(256, 3) void k3_proj(
    const bf16* __restrict__ A, const bf16* __restrict__ W,
    const float* __restrict__ bias, float* __restrict__ Out)
{
    __shared__ __align__(16) bf16 Bs[24576];
    unsigned id = blockIdx.x;                  // 2352 = 8 xcd * 49 mi * 6 n
    unsigned xcd = id & 7u, seq = id >> 3;     // 0..293
    unsigned mi = seq / 6u, nb = seq - mi * 6u;
    unsigned mblk = xcd + (mi << 3);
    unsigned tid = threadIdx.x;
    unsigned lane = tid & 63u, wv = tid >> 6;
    unsigned ln = lane & 15u, lq = lane >> 4;
    unsigned m0 = mblk * 256u, n0 = nb * 64u;

    for (unsigned c = tid; c < 3072u; c += 256u) {
        unsigned row = c / 48u, kc = c - row * 48u, k = kc * 8u;
        unsigned blk = (k >> 5) * 4u + (row >> 4);
        unsigned l = (row & 15u) | ((kc & 3u) << 4);
        *(int4*)&Bs[(blk * 64u + l) * 8u] = *(const int4*)(W + (size_t)(n0 + row) * 384u + k);
    }
    __syncthreads();

    f32x4 acc[4][4] = {};
    unsigned rbase = m0 + wv * 64u;

#pragma unroll
    for (unsigned kt = 0; kt < 12; ++kt) {
        bf16x8 af[4], bfr[4];
#pragma unroll
        for (unsigned i = 0; i < 4; ++i)
            af[i] = *(const bf16x8*)(A + (size_t)(rbase + i * 16u + ln) * 1152u +
                                     kt * 32u + lq * 8u);
#pragma unroll
        for (unsigned j = 0; j < 4; ++j)
            bfr[j] = *(const bf16x8*)&Bs[((kt * 4u + j) * 64u + lane) * 8u];
#pragma unroll
        for (unsigned i = 0; i < 4; ++i)
#pragma unroll
            for (unsigned j = 0; j < 4; ++j)
                acc[i][j] = MFMA16(af[i], bfr[j], acc[i][j]);
    }

#pragma unroll
    for (unsigned j = 0; j < 4; ++j) {
        unsigned col = n0 + j * 16u + ln;
        float bv = bias[col];
#pragma unroll
        for (unsigned i = 0; i < 4; ++i) {
            unsigned row = rbase + i * 16u + lq * 4u;
#pragma unroll
            for (unsigned rg = 0; rg < 4; ++rg)
                Out[(size_t)(row + rg) * 384u + col] = acc[i][j][rg] + bv;
        }
    }
}

// ---------------------------------------------------------------------------
// launch
// ---------------------------------------------------------------------------
extern "C" void kernel_launch(void* const* d_in, const int* in_sizes, int n_in,
                              void* d_out, int out_size, void* d_ws, size_t ws_size,
                              hipStream_t stream) {
    const float* x      = (const float*)d_in[0];
    const float* qkv_w  = (const float*)d_in[1];
    const float* qkv_b  = (const float*)d_in[2];
    const float* proj_w = (const float*)d_in[3];
    const float* proj_b = (const float*)d_in[4];
    const float* rpt    = (const float*)d_in[5];
    (void)in_sizes; (void)n_in; (void)out_size; (void)ws_size;

    char* ws = (char*)d_ws;
    bf16*  Y   = (bf16*)(ws);                       // 231,211,008 B
    bf16*  w1t = (bf16*)(ws + 231211008u);          //     884,736 B
    bf16*  w2t = (bf16*)(ws + 232095744u);          //     294,912 B
    float* BT  = (float*)(ws + 232390656u);         //     196,608 B
    float* out = (float*)d_out;

    k0_prep<<<2496, 256, 0, stream>>>(qkv_w, proj_w, rpt, w1t, w2t, BT);
    k1_qkv<<<7056, 256, 0, stream>>>(x, w1t, qkv_b, Y);
    k2_attn<<<dim3(12, 2048), 64, 0, stream>>>(Y, BT);
    k3_proj<<<2352, 256, 0, stream>>>(Y, w2t, proj_b, out);
}